// Round 12
// baseline (586.835 us; speedup 1.0000x reference)
//
#include <hip/hip_runtime.h>
#include <math.h>

#define BB 8
#define SS 2048
#define DDIM 512
#define KC 1536
#define EPSV 1e-6f
#define SCALE 0.044194173824159216f   // 1/sqrt(512)
#define LDP2 72   // padded LDS row for BK=64 tiles (64 + 8 bf16); odd 16B-unit stride -> <=2-way

typedef unsigned short ushort_t;
using short8 = __attribute__((ext_vector_type(8))) short;
using f32x4  = __attribute__((ext_vector_type(4))) float;

__device__ inline unsigned short f2bf(float f) {
    union { float f; unsigned int u; } v; v.f = f;
    unsigned int r = v.u + 0x7FFFu + ((v.u >> 16) & 1u);   // RNE
    return (unsigned short)(r >> 16);
}
__device__ inline unsigned int packbf(float a, float b) {
    return (unsigned int)f2bf(a) | ((unsigned int)f2bf(b) << 16);
}
__device__ inline float bf2f(unsigned short s) {
    union { unsigned int u; float f; } v; v.u = ((unsigned int)s) << 16; return v.f;
}
__device__ inline short8 ldfrag2(const ushort_t* s, int row, int ko) {
    return *reinterpret_cast<const short8*>(&s[row * LDP2 + ko]);
}

// ---------- kx: x fp32 -> bf16, and accumulate row-sums  xsum[b][d] = sum_s x ----------
__global__ __launch_bounds__(256) void kx_cast(const float* __restrict__ x,
                                               ushort_t* __restrict__ xbf,
                                               float* __restrict__ xsum)
{
    const int t = threadIdx.x;
    const int b = blockIdx.y;
    const int r0 = blockIdx.x * 16;
    const int c0 = 2 * t;
    float s0 = 0.f, s1 = 0.f;
    for (int r = 0; r < 16; r++) {
        size_t row = (size_t)b * SS + r0 + r;
        float2 v = *reinterpret_cast<const float2*>(&x[row * DDIM + c0]);
        s0 += v.x; s1 += v.y;
        *reinterpret_cast<unsigned int*>(&xbf[row * DDIM + c0]) = packbf(v.x, v.y);
    }
    atomicAdd(&xsum[b * DDIM + c0], s0);
    atomicAdd(&xsum[b * DDIM + c0 + 1], s1);
}

// ---------- k0: weights -> bf16 ----------
__global__ __launch_bounds__(256) void k0_prep(
    const float* __restrict__ conv_w, const float* __restrict__ Wq,
    const float* __restrict__ Wk, const float* __restrict__ Wv,
    ushort_t* __restrict__ wcat, ushort_t* __restrict__ wqkv)
{
    int idx = blockIdx.x * 256 + threadIdx.x;   // < 512*1536
    {   // wcat[o][t*512+i] = conv_w[o][i][t]
        int o = idx / KC, kk = idx - o * KC;
        int t = kk >> 9, i = kk & 511;
        wcat[idx] = f2bf(conv_w[(size_t)o * KC + i * 3 + t]);
    }
    {   // wqkv[n][d]
        int n = idx >> 9, d = idx & 511;
        const float* src = (n < 512) ? &Wq[(size_t)n * DDIM + d]
                         : (n < 1024) ? &Wk[(size_t)(n - 512) * DDIM + d]
                         : &Wv[(size_t)(n - 1024) * DDIM + d];
        wqkv[idx] = f2bf(*src);
    }
}

// ---------- k1b: conv as MFMA GEMM (K=1536 im2col), BK=64, y -> bf16 ----------
__global__ __launch_bounds__(256, 3) void k1b_conv(
    const ushort_t* __restrict__ xbf, const ushort_t* __restrict__ wcat,
    const float* __restrict__ conv_b, ushort_t* __restrict__ ybf, float* __restrict__ rs)
{
    __shared__ ushort_t As[128 * LDP2];
    __shared__ ushort_t Bs[128 * LDP2];
    const int t = threadIdx.x;
    const int lane = t & 63, w = t >> 6;
    const int lm = lane & 15, lq = lane >> 4;
    const int wm = w >> 1, wn = w & 1;
    const int sr = t >> 3, sc = (t & 7) * 8;   // staging: 32 rows/round, 4 rounds
    const int s0 = blockIdx.x * 128;
    const int n0 = blockIdx.y * 128;
    const int b  = blockIdx.z;
    const ushort_t* Ag = xbf + (size_t)b * SS * DDIM;
    const ushort_t* Bg = wcat + (size_t)n0 * KC;

    f32x4 acc[4][4];
    #pragma unroll
    for (int i = 0; i < 4; i++)
        #pragma unroll
        for (int j = 0; j < 4; j++) acc[i][j] = (f32x4){0.f, 0.f, 0.f, 0.f};

    const uint4 z4 = make_uint4(0, 0, 0, 0);
    uint4 ra[4], rb[4];
    #define LOADAB(dc) { \
        int tg_ = (dc) >> 3, ko_ = ((dc) & 7) * 64 + sc; \
        _Pragma("unroll") \
        for (int j = 0; j < 4; j++) { \
            int s_ = s0 + sr + j * 32 + tg_ - 1; \
            ra[j] = (s_ >= 0 && s_ < SS) ? *reinterpret_cast<const uint4*>(&Ag[(size_t)s_ * DDIM + ko_]) : z4; \
            rb[j] = *reinterpret_cast<const uint4*>(&Bg[(size_t)(sr + j * 32) * KC + (dc) * 64 + sc]); \
        } }

    LOADAB(0);
    for (int dc = 0; dc < 24; dc++) {
        #pragma unroll
        for (int j = 0; j < 4; j++) {
            *reinterpret_cast<uint4*>(&As[(sr + j * 32) * LDP2 + sc]) = ra[j];
            *reinterpret_cast<uint4*>(&Bs[(sr + j * 32) * LDP2 + sc]) = rb[j];
        }
        __syncthreads();
        if (dc < 23) LOADAB(dc + 1);
        #pragma unroll
        for (int half = 0; half < 2; half++) {
            short8 af[4];
            #pragma unroll
            for (int mt = 0; mt < 4; mt++)
                af[mt] = ldfrag2(As, wm * 64 + mt * 16 + lm, half * 32 + lq * 8);
            #pragma unroll
            for (int nt = 0; nt < 4; nt++) {
                short8 bfv = ldfrag2(Bs, wn * 64 + nt * 16 + lm, half * 32 + lq * 8);
                #pragma unroll
                for (int mt = 0; mt < 4; mt++)
                    acc[mt][nt] = __builtin_amdgcn_mfma_f32_16x16x32_bf16(af[mt], bfv, acc[mt][nt], 0, 0, 0);
            }
        }
        __syncthreads();
    }
    #undef LOADAB

    // epilogue: +bias, write y bf16, row sumsq atomics
    const int rbase = s0 + wm * 64;
    const int cbase = n0 + wn * 64;
    ushort_t* yb = ybf + (size_t)b * SS * DDIM;
    float* rsb = rs + (size_t)b * SS;
    float bias[4];
    #pragma unroll
    for (int nt = 0; nt < 4; nt++) bias[nt] = conv_b[cbase + nt * 16 + lm];
    #pragma unroll
    for (int mt = 0; mt < 4; mt++) {
        float pr[4] = {0.f, 0.f, 0.f, 0.f};
        #pragma unroll
        for (int nt = 0; nt < 4; nt++) {
            #pragma unroll
            for (int r = 0; r < 4; r++) {
                float val = acc[mt][nt][r] + bias[nt];
                yb[(size_t)(rbase + mt * 16 + lq * 4 + r) * DDIM + cbase + nt * 16 + lm] = f2bf(val);
                pr[r] = fmaf(val, val, pr[r]);
            }
        }
        #pragma unroll
        for (int r = 0; r < 4; r++) {
            float p = pr[r];
            p += __shfl_xor(p, 1, 64); p += __shfl_xor(p, 2, 64);
            p += __shfl_xor(p, 4, 64); p += __shfl_xor(p, 8, 64);
            if (lm == 0) atomicAdd(&rsb[rbase + mt * 16 + lq * 4 + r], p);
        }
    }
}

// ---------- k1n: x_norm = y * rsqrt(rs/D+eps) * pre_g ----------
__global__ __launch_bounds__(256) void k1n_norm(
    const ushort_t* __restrict__ ybf, const float* __restrict__ rs,
    const float* __restrict__ pre_g, ushort_t* __restrict__ xnbf)
{
    const int t = threadIdx.x;
    const int b = blockIdx.y;
    const int r0 = blockIdx.x * 8;
    float2 pg = *reinterpret_cast<const float2*>(&pre_g[2 * t]);
    for (int r = 0; r < 8; r++) {
        size_t row = (size_t)b * SS + r0 + r;
        float inv = rsqrtf(rs[row] * (1.0f / DDIM) + EPSV);
        unsigned int yv = *reinterpret_cast<const unsigned int*>(&ybf[row * DDIM + 2 * t]);
        float v0 = bf2f((ushort_t)(yv & 0xFFFF)), v1 = bf2f((ushort_t)(yv >> 16));
        *reinterpret_cast<unsigned int*>(&xnbf[row * DDIM + 2 * t]) =
            packbf(v0 * inv * pg.x, v1 * inv * pg.y);
    }
}

// ---------- k1c: QKV GEMM (N=1536 concat), BK=64 ----------
__global__ __launch_bounds__(256, 3) void k1c_qkv(
    const ushort_t* __restrict__ xnbf, const ushort_t* __restrict__ wqkv,
    ushort_t* __restrict__ qraw, ushort_t* __restrict__ kraw, ushort_t* __restrict__ vb,
    float* __restrict__ rq, float* __restrict__ rk)
{
    __shared__ ushort_t As[128 * LDP2];
    __shared__ ushort_t Bs[128 * LDP2];
    const int t = threadIdx.x;
    const int lane = t & 63, w = t >> 6;
    const int lm = lane & 15, lq = lane >> 4;
    const int wm = w >> 1, wn = w & 1;
    const int sr = t >> 3, sc = (t & 7) * 8;
    const int s0 = blockIdx.x * 128;
    const int n0 = blockIdx.y * 128;
    const int b  = blockIdx.z;
    const ushort_t* Ag = xnbf + ((size_t)b * SS + s0) * DDIM;
    const ushort_t* Bg = wqkv + (size_t)n0 * DDIM;

    f32x4 acc[4][4];
    #pragma unroll
    for (int i = 0; i < 4; i++)
        #pragma unroll
        for (int j = 0; j < 4; j++) acc[i][j] = (f32x4){0.f, 0.f, 0.f, 0.f};

    uint4 ra[4], rb[4];
    #define LOADAB2(dc) { \
        int ko_ = (dc) * 64 + sc; \
        _Pragma("unroll") \
        for (int j = 0; j < 4; j++) { \
            ra[j] = *reinterpret_cast<const uint4*>(&Ag[(size_t)(sr + j * 32) * DDIM + ko_]); \
            rb[j] = *reinterpret_cast<const uint4*>(&Bg[(size_t)(sr + j * 32) * DDIM + ko_]); \
        } }

    LOADAB2(0);
    for (int dc = 0; dc < 8; dc++) {
        #pragma unroll
        for (int j = 0; j < 4; j++) {
            *reinterpret_cast<uint4*>(&As[(sr + j * 32) * LDP2 + sc]) = ra[j];
            *reinterpret_cast<uint4*>(&Bs[(sr + j * 32) * LDP2 + sc]) = rb[j];
        }
        __syncthreads();
        if (dc < 7) LOADAB2(dc + 1);
        #pragma unroll
        for (int half = 0; half < 2; half++) {
            short8 af[4];
            #pragma unroll
            for (int mt = 0; mt < 4; mt++)
                af[mt] = ldfrag2(As, wm * 64 + mt * 16 + lm, half * 32 + lq * 8);
            #pragma unroll
            for (int nt = 0; nt < 4; nt++) {
                short8 bfv = ldfrag2(Bs, wn * 64 + nt * 16 + lm, half * 32 + lq * 8);
                #pragma unroll
                for (int mt = 0; mt < 4; mt++)
                    acc[mt][nt] = __builtin_amdgcn_mfma_f32_16x16x32_bf16(af[mt], bfv, acc[mt][nt], 0, 0, 0);
            }
        }
        __syncthreads();
    }
    #undef LOADAB2

    const int which = blockIdx.y >> 2;              // 0=q 1=k 2=v
    const int rbase = s0 + wm * 64;
    const int cbase = ((blockIdx.y & 3) * 128) + wn * 64;
    if (which == 2) {
        ushort_t* vbb = vb + (size_t)b * SS * DDIM;
        #pragma unroll
        for (int mt = 0; mt < 4; mt++)
            #pragma unroll
            for (int nt = 0; nt < 4; nt++)
                #pragma unroll
                for (int r = 0; r < 4; r++)
                    vbb[(size_t)(rbase + mt * 16 + lq * 4 + r) * DDIM + cbase + nt * 16 + lm] =
                        f2bf(acc[mt][nt][r]);
    } else {
        ushort_t* db = (which ? kraw : qraw) + (size_t)b * SS * DDIM;
        float* rb2 = (which ? rk : rq) + (size_t)b * SS;
        #pragma unroll
        for (int mt = 0; mt < 4; mt++) {
            float pr[4] = {0.f, 0.f, 0.f, 0.f};
            #pragma unroll
            for (int nt = 0; nt < 4; nt++) {
                #pragma unroll
                for (int r = 0; r < 4; r++) {
                    float val = acc[mt][nt][r];
                    db[(size_t)(rbase + mt * 16 + lq * 4 + r) * DDIM + cbase + nt * 16 + lm] = f2bf(val);
                    pr[r] = fmaf(val, val, pr[r]);
                }
            }
            #pragma unroll
            for (int r = 0; r < 4; r++) {
                float p = pr[r];
                p += __shfl_xor(p, 1, 64); p += __shfl_xor(p, 2, 64);
                p += __shfl_xor(p, 4, 64); p += __shfl_xor(p, 8, 64);
                if (lm == 0) atomicAdd(&rb2[rbase + mt * 16 + lq * 4 + r], p);
            }
        }
    }
}

// ---------- k1d: rmsnorm(q,k) + rope, in-place ----------
__global__ __launch_bounds__(256) void k1d_rope(
    ushort_t* q_io, ushort_t* k_io,
    const float* __restrict__ rq, const float* __restrict__ rk,
    const float* __restrict__ q_g, const float* __restrict__ k_g)
{
    const int t = threadIdx.x;
    const int b = blockIdx.y;
    const int r0 = blockIdx.x * 8;
    const int c0 = 2 * t;
    float qg0 = q_g[c0], qg1 = q_g[c0 + 1];
    float kg0 = k_g[c0], kg1 = k_g[c0 + 1];
    float invf = (float)pow(10000.0, -(double)c0 / (double)DDIM);
    for (int r = 0; r < 8; r++) {
        int srow = r0 + r;
        size_t rowi = (size_t)b * SS + srow;
        float iq = rsqrtf(rq[rowi] * (1.0f / DDIM) + EPSV);
        float ik = rsqrtf(rk[rowi] * (1.0f / DDIM) + EPSV);
        size_t off = rowi * DDIM + c0;
        unsigned int qv = *reinterpret_cast<const unsigned int*>(&q_io[off]);
        unsigned int kv = *reinterpret_cast<const unsigned int*>(&k_io[off]);
        float q0 = bf2f((ushort_t)(qv & 0xFFFF)) * iq * qg0;
        float q1 = bf2f((ushort_t)(qv >> 16)) * iq * qg1;
        float k0v = bf2f((ushort_t)(kv & 0xFFFF)) * ik * kg0;
        float k1v = bf2f((ushort_t)(kv >> 16)) * ik * kg1;
        float ang = (float)srow * invf, sn, cs;
        sincosf(ang, &sn, &cs);
        *reinterpret_cast<unsigned int*>(&q_io[off]) = packbf(q0 * cs - q1 * sn, q0 * sn + q1 * cs);
        *reinterpret_cast<unsigned int*>(&k_io[off]) = packbf(k0v * cs - k1v * sn, k0v * sn + k1v * cs);
    }
}

// ---------- k2a: scores GEMM (BK=64) -> P (bf16 unnormalized exp) + row sums l ----------
// Grid (BB, qtile, ktile): block id % 8 == batch -> XCD-affine; per-batch Q+K fits L2.
__global__ __launch_bounds__(256, 3) void k2a_rowsum(
    const ushort_t* __restrict__ qb, const ushort_t* __restrict__ kb,
    ushort_t* __restrict__ P, float* __restrict__ l)
{
    __shared__ ushort_t As[128 * LDP2];
    __shared__ ushort_t Bs[128 * LDP2];
    const int t = threadIdx.x;
    const int lane = t & 63, w = t >> 6;
    const int lm = lane & 15, lq = lane >> 4;
    const int wm = w >> 1, wn = w & 1;
    const int sr = t >> 3, sc = (t & 7) * 8;
    const int b  = blockIdx.x;
    const int qt = blockIdx.y;
    const int kt = blockIdx.z;

    const ushort_t* Ag = qb + ((size_t)b * SS + qt * 128) * DDIM;
    const ushort_t* Bg = kb + ((size_t)b * SS + kt * 128) * DDIM;

    f32x4 acc[4][4];
    #pragma unroll
    for (int i = 0; i < 4; i++)
        #pragma unroll
        for (int j = 0; j < 4; j++) acc[i][j] = (f32x4){0.f, 0.f, 0.f, 0.f};

    uint4 ra[4], rb[4];
    #define LOADAB3(dc) { \
        int ko_ = (dc) * 64 + sc; \
        _Pragma("unroll") \
        for (int j = 0; j < 4; j++) { \
            ra[j] = *reinterpret_cast<const uint4*>(&Ag[(size_t)(sr + j * 32) * DDIM + ko_]); \
            rb[j] = *reinterpret_cast<const uint4*>(&Bg[(size_t)(sr + j * 32) * DDIM + ko_]); \
        } }

    LOADAB3(0);
    for (int dc = 0; dc < 8; dc++) {
        #pragma unroll
        for (int j = 0; j < 4; j++) {
            *reinterpret_cast<uint4*>(&As[(sr + j * 32) * LDP2 + sc]) = ra[j];
            *reinterpret_cast<uint4*>(&Bs[(sr + j * 32) * LDP2 + sc]) = rb[j];
        }
        __syncthreads();
        if (dc < 7) LOADAB3(dc + 1);
        #pragma unroll
        for (int half = 0; half < 2; half++) {
            short8 af[4];
            #pragma unroll
            for (int mt = 0; mt < 4; mt++)
                af[mt] = ldfrag2(As, wm * 64 + mt * 16 + lm, half * 32 + lq * 8);
            #pragma unroll
            for (int nt = 0; nt < 4; nt++) {
                short8 bfv = ldfrag2(Bs, wn * 64 + nt * 16 + lm, half * 32 + lq * 8);
                #pragma unroll
                for (int mt = 0; mt < 4; mt++)
                    acc[mt][nt] = __builtin_amdgcn_mfma_f32_16x16x32_bf16(af[mt], bfv, acc[mt][nt], 0, 0, 0);
            }
        }
        __syncthreads();
    }
    #undef LOADAB3

    const int rbase = qt * 128 + wm * 64;
    const int cbase = kt * 128 + wn * 64;
    ushort_t* Pb = P + (size_t)b * SS * SS;
    float* lrow = l + (size_t)b * SS;
    #pragma unroll
    for (int mt = 0; mt < 4; mt++) {
        #pragma unroll
        for (int r = 0; r < 4; r++) {
            const int row = rbase + mt * 16 + lq * 4 + r;
            float rowp = 0.f;
            #pragma unroll
            for (int nt = 0; nt < 4; nt++) {
                float e = __expf(acc[mt][nt][r] * SCALE);
                Pb[(size_t)row * SS + cbase + nt * 16 + lm] = f2bf(e);
                rowp += e;
            }
            float p = rowp;
            p += __shfl_xor(p, 1, 64); p += __shfl_xor(p, 2, 64);
            p += __shfl_xor(p, 4, 64); p += __shfl_xor(p, 8, 64);
            if (lm == 0) atomicAdd(&lrow[row], p);
        }
    }
}

// ---------- k2c: cw[k] = sum_q P[q][k] / l[q] ----------
__global__ __launch_bounds__(256) void k2c_colred(
    const ushort_t* __restrict__ P, const float* __restrict__ l,
    float* __restrict__ cw)
{
    const int t = threadIdx.x;
    const int b = blockIdx.z;
    const int k0 = blockIdx.x * 1024 + t * 4;
    const int q0 = blockIdx.y * 128;
    const ushort_t* Pb = P + ((size_t)b * SS + q0) * SS;
    const float* lb = l + (size_t)b * SS + q0;
    float a0 = 0.f, a1 = 0.f, a2 = 0.f, a3 = 0.f;
    for (int q = 0; q < 128; q++) {
        float rl = 1.0f / lb[q];
        uint2 pp = *reinterpret_cast<const uint2*>(&Pb[(size_t)q * SS + k0]);
        a0 = fmaf(bf2f((ushort_t)(pp.x & 0xFFFF)), rl, a0);
        a1 = fmaf(bf2f((ushort_t)(pp.x >> 16)), rl, a1);
        a2 = fmaf(bf2f((ushort_t)(pp.y & 0xFFFF)), rl, a2);
        a3 = fmaf(bf2f((ushort_t)(pp.y >> 16)), rl, a3);
    }
    atomicAdd(&cw[(size_t)b * SS + k0], a0);
    atomicAdd(&cw[(size_t)b * SS + k0 + 1], a1);
    atomicAdd(&cw[(size_t)b * SS + k0 + 2], a2);
    atomicAdd(&cw[(size_t)b * SS + k0 + 3], a3);
}

// ---------- k4: out = (xsum + sum_k cw*v) / S ----------
__global__ __launch_bounds__(256) void k4_out(
    const float* __restrict__ xsum, const ushort_t* __restrict__ v,
    const float* __restrict__ cwv, float* __restrict__ out)
{
    const int b = blockIdx.x, c = blockIdx.y;
    const int t = threadIdx.x;
    const int srow0 = c * (SS / 16);
    const ushort_t* vb = v + ((size_t)b * SS + srow0) * DDIM;
    const float* cwb   = cwv + (size_t)b * SS + srow0;
    float a0 = (c == 0) ? xsum[b * DDIM + t]       : 0.f;
    float a1 = (c == 0) ? xsum[b * DDIM + t + 256] : 0.f;
    for (int r = 0; r < SS / 16; r++) {
        float w = cwb[r];
        a0 += w * bf2f(vb[(size_t)r * DDIM + t]);
        a1 += w * bf2f(vb[(size_t)r * DDIM + t + 256]);
    }
    atomicAdd(&out[b * DDIM + t],       a0 * (1.0f / SS));
    atomicAdd(&out[b * DDIM + t + 256], a1 * (1.0f / SS));
}

extern "C" void kernel_launch(void* const* d_in, const int* in_sizes, int n_in,
                              void* d_out, int out_size, void* d_ws, size_t ws_size,
                              hipStream_t stream)
{
    const float* x      = (const float*)d_in[0];
    const float* conv_w = (const float*)d_in[1];
    const float* conv_b = (const float*)d_in[2];
    const float* pre_g  = (const float*)d_in[3];
    const float* q_g    = (const float*)d_in[4];
    const float* k_g    = (const float*)d_in[5];
    const float* Wq     = (const float*)d_in[6];
    const float* Wk     = (const float*)d_in[7];
    const float* Wv     = (const float*)d_in[8];
    float* out          = (float*)d_out;

    const size_t NTOK = (size_t)BB * SS * DDIM;   // 8.39M elements
    char* p = (char*)d_ws;
    // P region: 4 x NTOK bf16 = exactly BB*SS*SS*2 = 67.1 MB; sub-buffers dead by k2a.
    ushort_t* xbf = (ushort_t*)p; p += NTOK * 2;
    ushort_t* ybf = (ushort_t*)p; p += NTOK * 2;
    ushort_t* xn  = (ushort_t*)p; p += NTOK * 2;
    /* pad */                     p += NTOK * 2;
    ushort_t* qio = (ushort_t*)p; p += NTOK * 2;
    ushort_t* kio = (ushort_t*)p; p += NTOK * 2;
    ushort_t* vb  = (ushort_t*)p; p += NTOK * 2;
    ushort_t* wcat = (ushort_t*)p; p += (size_t)DDIM * KC * 2;
    ushort_t* wqkv = (ushort_t*)p; p += (size_t)KC * DDIM * 2;
    float* rs   = (float*)p; p += (size_t)BB * SS * 4;
    float* rq   = (float*)p; p += (size_t)BB * SS * 4;
    float* rk   = (float*)p; p += (size_t)BB * SS * 4;
    float* lbuf = (float*)p; p += (size_t)BB * SS * 4;
    float* cwb  = (float*)p; p += (size_t)BB * SS * 4;
    float* xsum = (float*)p; p += (size_t)BB * DDIM * 4;

    ushort_t* Pbuf = xbf;   // 67.1 MB aliased region

    (void)hipMemsetAsync(d_out, 0, (size_t)out_size * sizeof(float), stream);
    (void)hipMemsetAsync(rs, 0, ((size_t)BB * SS * 5 + (size_t)BB * DDIM) * sizeof(float), stream);

    kx_cast<<<dim3(SS / 16, BB), 256, 0, stream>>>(x, xbf, xsum);
    k0_prep<<<dim3(DDIM * KC / 256), 256, 0, stream>>>(conv_w, Wq, Wk, Wv, wcat, wqkv);
    k1b_conv<<<dim3(SS / 128, 4, BB), 256, 0, stream>>>(xbf, wcat, conv_b, ybf, rs);
    k1n_norm<<<dim3(SS / 8, BB), 256, 0, stream>>>(ybf, rs, pre_g, xn);
    k1c_qkv<<<dim3(SS / 128, 12, BB), 256, 0, stream>>>(xn, wqkv, qio, kio, vb, rq, rk);
    k1d_rope<<<dim3(SS / 8, BB), 256, 0, stream>>>(qio, kio, rq, rk, q_g, k_g);
    k2a_rowsum<<<dim3(BB, SS / 128, SS / 128), 256, 0, stream>>>(qio, kio, Pbuf, lbuf);
    k2c_colred<<<dim3(SS / 1024, SS / 128, BB), 256, 0, stream>>>(Pbuf, lbuf, cwb);
    k4_out<<<dim3(BB, 16), 256, 0, stream>>>(xsum, vb, cwb, out);
}

// Round 13
// 289.376 us; speedup vs baseline: 2.0279x; 2.0279x over previous
//
#include <hip/hip_runtime.h>
#include <math.h>

#define BB 8
#define SS 2048
#define DDIM 512
#define KC 1536
#define EPSV 1e-6f
#define SCALE 0.044194173824159216f   // 1/sqrt(512)
#define LDP2 72   // padded LDS row for BK=64 tiles (64 + 8 bf16)

typedef unsigned short ushort_t;
using short8 = __attribute__((ext_vector_type(8))) short;
using f32x4  = __attribute__((ext_vector_type(4))) float;

__device__ inline unsigned short f2bf(float f) {
    union { float f; unsigned int u; } v; v.f = f;
    unsigned int r = v.u + 0x7FFFu + ((v.u >> 16) & 1u);   // RNE
    return (unsigned short)(r >> 16);
}
__device__ inline unsigned int packbf(float a, float b) {
    return (unsigned int)f2bf(a) | ((unsigned int)f2bf(b) << 16);
}
__device__ inline float bf2f(unsigned short s) {
    union { unsigned int u; float f; } v; v.u = ((unsigned int)s) << 16; return v.f;
}
__device__ inline short8 ldfrag2(const ushort_t* s, int row, int ko) {
    return *reinterpret_cast<const short8*>(&s[row * LDP2 + ko]);
}
__device__ inline uint4 lda_bc(const ushort_t* Ag, int s_, int ko) {
    return (s_ >= 0 && s_ < SS) ? *reinterpret_cast<const uint4*>(&Ag[(size_t)s_ * DDIM + ko])
                                : make_uint4(0, 0, 0, 0);
}

// ---------- kx: x fp32 -> bf16, plus xsum[b][d] = sum_s x ----------
__global__ __launch_bounds__(256) void kx_cast(const float* __restrict__ x,
                                               ushort_t* __restrict__ xbf,
                                               float* __restrict__ xsum)
{
    const int t = threadIdx.x;
    const int b = blockIdx.y;
    const int r0 = blockIdx.x * 16;
    const int c0 = 2 * t;
    float s0 = 0.f, s1 = 0.f;
    for (int r = 0; r < 16; r++) {
        size_t row = (size_t)b * SS + r0 + r;
        float2 v = *reinterpret_cast<const float2*>(&x[row * DDIM + c0]);
        s0 += v.x; s1 += v.y;
        *reinterpret_cast<unsigned int*>(&xbf[row * DDIM + c0]) = packbf(v.x, v.y);
    }
    atomicAdd(&xsum[b * DDIM + c0], s0);
    atomicAdd(&xsum[b * DDIM + c0 + 1], s1);
}

// ---------- k0: weights -> bf16 ----------
__global__ __launch_bounds__(256) void k0_prep(
    const float* __restrict__ conv_w, const float* __restrict__ Wq,
    const float* __restrict__ Wk, const float* __restrict__ Wv,
    ushort_t* __restrict__ wcat, ushort_t* __restrict__ wqkv)
{
    int idx = blockIdx.x * 256 + threadIdx.x;   // < 512*1536
    {
        int o = idx / KC, kk = idx - o * KC;
        int t = kk >> 9, i = kk & 511;
        wcat[idx] = f2bf(conv_w[(size_t)o * KC + i * 3 + t]);
    }
    {
        int n = idx >> 9, d = idx & 511;
        const float* src = (n < 512) ? &Wq[(size_t)n * DDIM + d]
                         : (n < 1024) ? &Wk[(size_t)(n - 512) * DDIM + d]
                         : &Wv[(size_t)(n - 1024) * DDIM + d];
        wqkv[idx] = f2bf(*src);
    }
}

// ---------- k1b: conv GEMM, BK=64 (K=1536), named prefetch regs ----------
__global__ __launch_bounds__(256) void k1b_conv(
    const ushort_t* __restrict__ xbf, const ushort_t* __restrict__ wcat,
    const float* __restrict__ conv_b, ushort_t* __restrict__ ybf, float* __restrict__ rs)
{
    __shared__ ushort_t As[128 * LDP2];
    __shared__ ushort_t Bs[128 * LDP2];
    const int t = threadIdx.x;
    const int lane = t & 63, w = t >> 6;
    const int lm = lane & 15, lq = lane >> 4;
    const int wm = w >> 1, wn = w & 1;
    const int sr = t >> 3, sc = (t & 7) * 8;   // staging: 32 rows x 64 cols per round, 4 rounds
    const int s0 = blockIdx.x * 128;
    const int n0 = blockIdx.y * 128;
    const int b  = blockIdx.z;
    const ushort_t* Ag = xbf + (size_t)b * SS * DDIM;
    const ushort_t* Bg = wcat + (size_t)n0 * KC;

    f32x4 acc[4][4];
    #pragma unroll
    for (int i = 0; i < 4; i++)
        #pragma unroll
        for (int j = 0; j < 4; j++) acc[i][j] = (f32x4){0.f, 0.f, 0.f, 0.f};

    uint4 ra0, ra1, ra2, ra3, rb0, rb1, rb2, rb3;
    #define LOADAB(dc) { \
        int tg_ = (dc) >> 3, ko_ = ((dc) & 7) * 64 + sc, kb_ = (dc) * 64 + sc; \
        int sa_ = s0 + sr + tg_ - 1; \
        ra0 = lda_bc(Ag, sa_,      ko_); ra1 = lda_bc(Ag, sa_ + 32, ko_); \
        ra2 = lda_bc(Ag, sa_ + 64, ko_); ra3 = lda_bc(Ag, sa_ + 96, ko_); \
        rb0 = *reinterpret_cast<const uint4*>(&Bg[(size_t)sr * KC + kb_]); \
        rb1 = *reinterpret_cast<const uint4*>(&Bg[(size_t)(sr + 32) * KC + kb_]); \
        rb2 = *reinterpret_cast<const uint4*>(&Bg[(size_t)(sr + 64) * KC + kb_]); \
        rb3 = *reinterpret_cast<const uint4*>(&Bg[(size_t)(sr + 96) * KC + kb_]); }

    LOADAB(0);
    for (int dc = 0; dc < 24; dc++) {
        *reinterpret_cast<uint4*>(&As[(sr)      * LDP2 + sc]) = ra0;
        *reinterpret_cast<uint4*>(&As[(sr + 32) * LDP2 + sc]) = ra1;
        *reinterpret_cast<uint4*>(&As[(sr + 64) * LDP2 + sc]) = ra2;
        *reinterpret_cast<uint4*>(&As[(sr + 96) * LDP2 + sc]) = ra3;
        *reinterpret_cast<uint4*>(&Bs[(sr)      * LDP2 + sc]) = rb0;
        *reinterpret_cast<uint4*>(&Bs[(sr + 32) * LDP2 + sc]) = rb1;
        *reinterpret_cast<uint4*>(&Bs[(sr + 64) * LDP2 + sc]) = rb2;
        *reinterpret_cast<uint4*>(&Bs[(sr + 96) * LDP2 + sc]) = rb3;
        __syncthreads();
        if (dc < 23) LOADAB(dc + 1);
        #pragma unroll
        for (int half = 0; half < 2; half++) {
            short8 af0 = ldfrag2(As, wm * 64 +  0 + lm, half * 32 + lq * 8);
            short8 af1 = ldfrag2(As, wm * 64 + 16 + lm, half * 32 + lq * 8);
            short8 af2 = ldfrag2(As, wm * 64 + 32 + lm, half * 32 + lq * 8);
            short8 af3 = ldfrag2(As, wm * 64 + 48 + lm, half * 32 + lq * 8);
            #pragma unroll
            for (int nt = 0; nt < 4; nt++) {
                short8 bfv = ldfrag2(Bs, wn * 64 + nt * 16 + lm, half * 32 + lq * 8);
                acc[0][nt] = __builtin_amdgcn_mfma_f32_16x16x32_bf16(af0, bfv, acc[0][nt], 0, 0, 0);
                acc[1][nt] = __builtin_amdgcn_mfma_f32_16x16x32_bf16(af1, bfv, acc[1][nt], 0, 0, 0);
                acc[2][nt] = __builtin_amdgcn_mfma_f32_16x16x32_bf16(af2, bfv, acc[2][nt], 0, 0, 0);
                acc[3][nt] = __builtin_amdgcn_mfma_f32_16x16x32_bf16(af3, bfv, acc[3][nt], 0, 0, 0);
            }
        }
        __syncthreads();
    }
    #undef LOADAB

    const int rbase = s0 + wm * 64;
    const int cbase = n0 + wn * 64;
    ushort_t* yb = ybf + (size_t)b * SS * DDIM;
    float* rsb = rs + (size_t)b * SS;
    float bias[4];
    #pragma unroll
    for (int nt = 0; nt < 4; nt++) bias[nt] = conv_b[cbase + nt * 16 + lm];
    #pragma unroll
    for (int mt = 0; mt < 4; mt++) {
        float pr[4] = {0.f, 0.f, 0.f, 0.f};
        #pragma unroll
        for (int nt = 0; nt < 4; nt++) {
            #pragma unroll
            for (int r = 0; r < 4; r++) {
                float val = acc[mt][nt][r] + bias[nt];
                yb[(size_t)(rbase + mt * 16 + lq * 4 + r) * DDIM + cbase + nt * 16 + lm] = f2bf(val);
                pr[r] = fmaf(val, val, pr[r]);
            }
        }
        #pragma unroll
        for (int r = 0; r < 4; r++) {
            float p = pr[r];
            p += __shfl_xor(p, 1, 64); p += __shfl_xor(p, 2, 64);
            p += __shfl_xor(p, 4, 64); p += __shfl_xor(p, 8, 64);
            if (lm == 0) atomicAdd(&rsb[rbase + mt * 16 + lq * 4 + r], p);
        }
    }
}

// ---------- k1n: x_norm ----------
__global__ __launch_bounds__(256) void k1n_norm(
    const ushort_t* __restrict__ ybf, const float* __restrict__ rs,
    const float* __restrict__ pre_g, ushort_t* __restrict__ xnbf)
{
    const int t = threadIdx.x;
    const int b = blockIdx.y;
    const int r0 = blockIdx.x * 8;
    float2 pg = *reinterpret_cast<const float2*>(&pre_g[2 * t]);
    for (int r = 0; r < 8; r++) {
        size_t row = (size_t)b * SS + r0 + r;
        float inv = rsqrtf(rs[row] * (1.0f / DDIM) + EPSV);
        unsigned int yv = *reinterpret_cast<const unsigned int*>(&ybf[row * DDIM + 2 * t]);
        float v0 = bf2f((ushort_t)(yv & 0xFFFF)), v1 = bf2f((ushort_t)(yv >> 16));
        *reinterpret_cast<unsigned int*>(&xnbf[row * DDIM + 2 * t]) =
            packbf(v0 * inv * pg.x, v1 * inv * pg.y);
    }
}

// ---------- k1c: QKV GEMM, BK=64 ----------
__global__ __launch_bounds__(256) void k1c_qkv(
    const ushort_t* __restrict__ xnbf, const ushort_t* __restrict__ wqkv,
    ushort_t* __restrict__ qraw, ushort_t* __restrict__ kraw, ushort_t* __restrict__ vb,
    float* __restrict__ rq, float* __restrict__ rk)
{
    __shared__ ushort_t As[128 * LDP2];
    __shared__ ushort_t Bs[128 * LDP2];
    const int t = threadIdx.x;
    const int lane = t & 63, w = t >> 6;
    const int lm = lane & 15, lq = lane >> 4;
    const int wm = w >> 1, wn = w & 1;
    const int sr = t >> 3, sc = (t & 7) * 8;
    const int s0 = blockIdx.x * 128;
    const int n0 = blockIdx.y * 128;
    const int b  = blockIdx.z;
    const ushort_t* Ag = xnbf + ((size_t)b * SS + s0) * DDIM;
    const ushort_t* Bg = wqkv + (size_t)n0 * DDIM;

    f32x4 acc[4][4];
    #pragma unroll
    for (int i = 0; i < 4; i++)
        #pragma unroll
        for (int j = 0; j < 4; j++) acc[i][j] = (f32x4){0.f, 0.f, 0.f, 0.f};

    uint4 ra0, ra1, ra2, ra3, rb0, rb1, rb2, rb3;
    #define LOADAB2(dc) { \
        int ko_ = (dc) * 64 + sc; \
        ra0 = *reinterpret_cast<const uint4*>(&Ag[(size_t)sr * DDIM + ko_]); \
        ra1 = *reinterpret_cast<const uint4*>(&Ag[(size_t)(sr + 32) * DDIM + ko_]); \
        ra2 = *reinterpret_cast<const uint4*>(&Ag[(size_t)(sr + 64) * DDIM + ko_]); \
        ra3 = *reinterpret_cast<const uint4*>(&Ag[(size_t)(sr + 96) * DDIM + ko_]); \
        rb0 = *reinterpret_cast<const uint4*>(&Bg[(size_t)sr * DDIM + ko_]); \
        rb1 = *reinterpret_cast<const uint4*>(&Bg[(size_t)(sr + 32) * DDIM + ko_]); \
        rb2 = *reinterpret_cast<const uint4*>(&Bg[(size_t)(sr + 64) * DDIM + ko_]); \
        rb3 = *reinterpret_cast<const uint4*>(&Bg[(size_t)(sr + 96) * DDIM + ko_]); }

    LOADAB2(0);
    for (int dc = 0; dc < 8; dc++) {
        *reinterpret_cast<uint4*>(&As[(sr)      * LDP2 + sc]) = ra0;
        *reinterpret_cast<uint4*>(&As[(sr + 32) * LDP2 + sc]) = ra1;
        *reinterpret_cast<uint4*>(&As[(sr + 64) * LDP2 + sc]) = ra2;
        *reinterpret_cast<uint4*>(&As[(sr + 96) * LDP2 + sc]) = ra3;
        *reinterpret_cast<uint4*>(&Bs[(sr)      * LDP2 + sc]) = rb0;
        *reinterpret_cast<uint4*>(&Bs[(sr + 32) * LDP2 + sc]) = rb1;
        *reinterpret_cast<uint4*>(&Bs[(sr + 64) * LDP2 + sc]) = rb2;
        *reinterpret_cast<uint4*>(&Bs[(sr + 96) * LDP2 + sc]) = rb3;
        __syncthreads();
        if (dc < 7) LOADAB2(dc + 1);
        #pragma unroll
        for (int half = 0; half < 2; half++) {
            short8 af0 = ldfrag2(As, wm * 64 +  0 + lm, half * 32 + lq * 8);
            short8 af1 = ldfrag2(As, wm * 64 + 16 + lm, half * 32 + lq * 8);
            short8 af2 = ldfrag2(As, wm * 64 + 32 + lm, half * 32 + lq * 8);
            short8 af3 = ldfrag2(As, wm * 64 + 48 + lm, half * 32 + lq * 8);
            #pragma unroll
            for (int nt = 0; nt < 4; nt++) {
                short8 bfv = ldfrag2(Bs, wn * 64 + nt * 16 + lm, half * 32 + lq * 8);
                acc[0][nt] = __builtin_amdgcn_mfma_f32_16x16x32_bf16(af0, bfv, acc[0][nt], 0, 0, 0);
                acc[1][nt] = __builtin_amdgcn_mfma_f32_16x16x32_bf16(af1, bfv, acc[1][nt], 0, 0, 0);
                acc[2][nt] = __builtin_amdgcn_mfma_f32_16x16x32_bf16(af2, bfv, acc[2][nt], 0, 0, 0);
                acc[3][nt] = __builtin_amdgcn_mfma_f32_16x16x32_bf16(af3, bfv, acc[3][nt], 0, 0, 0);
            }
        }
        __syncthreads();
    }
    #undef LOADAB2

    const int which = blockIdx.y >> 2;              // 0=q 1=k 2=v
    const int rbase = s0 + wm * 64;
    const int cbase = ((blockIdx.y & 3) * 128) + wn * 64;
    if (which == 2) {
        ushort_t* vbb = vb + (size_t)b * SS * DDIM;
        #pragma unroll
        for (int mt = 0; mt < 4; mt++)
            #pragma unroll
            for (int nt = 0; nt < 4; nt++)
                #pragma unroll
                for (int r = 0; r < 4; r++)
                    vbb[(size_t)(rbase + mt * 16 + lq * 4 + r) * DDIM + cbase + nt * 16 + lm] =
                        f2bf(acc[mt][nt][r]);
    } else {
        ushort_t* db = (which ? kraw : qraw) + (size_t)b * SS * DDIM;
        float* rb = (which ? rk : rq) + (size_t)b * SS;
        #pragma unroll
        for (int mt = 0; mt < 4; mt++) {
            float pr[4] = {0.f, 0.f, 0.f, 0.f};
            #pragma unroll
            for (int nt = 0; nt < 4; nt++) {
                #pragma unroll
                for (int r = 0; r < 4; r++) {
                    float val = acc[mt][nt][r];
                    db[(size_t)(rbase + mt * 16 + lq * 4 + r) * DDIM + cbase + nt * 16 + lm] = f2bf(val);
                    pr[r] = fmaf(val, val, pr[r]);
                }
            }
            #pragma unroll
            for (int r = 0; r < 4; r++) {
                float p = pr[r];
                p += __shfl_xor(p, 1, 64); p += __shfl_xor(p, 2, 64);
                p += __shfl_xor(p, 4, 64); p += __shfl_xor(p, 8, 64);
                if (lm == 0) atomicAdd(&rb[rbase + mt * 16 + lq * 4 + r], p);
            }
        }
    }
}

// ---------- k1d: rmsnorm(q,k) + rope, in-place ----------
__global__ __launch_bounds__(256) void k1d_rope(
    ushort_t* q_io, ushort_t* k_io,
    const float* __restrict__ rq, const float* __restrict__ rk,
    const float* __restrict__ q_g, const float* __restrict__ k_g)
{
    const int t = threadIdx.x;
    const int b = blockIdx.y;
    const int r0 = blockIdx.x * 8;
    const int c0 = 2 * t;
    float qg0 = q_g[c0], qg1 = q_g[c0 + 1];
    float kg0 = k_g[c0], kg1 = k_g[c0 + 1];
    float invf = (float)pow(10000.0, -(double)c0 / (double)DDIM);
    for (int r = 0; r < 8; r++) {
        int srow = r0 + r;
        size_t rowi = (size_t)b * SS + srow;
        float iq = rsqrtf(rq[rowi] * (1.0f / DDIM) + EPSV);
        float ik = rsqrtf(rk[rowi] * (1.0f / DDIM) + EPSV);
        size_t off = rowi * DDIM + c0;
        unsigned int qv = *reinterpret_cast<const unsigned int*>(&q_io[off]);
        unsigned int kv = *reinterpret_cast<const unsigned int*>(&k_io[off]);
        float q0 = bf2f((ushort_t)(qv & 0xFFFF)) * iq * qg0;
        float q1 = bf2f((ushort_t)(qv >> 16)) * iq * qg1;
        float k0v = bf2f((ushort_t)(kv & 0xFFFF)) * ik * kg0;
        float k1v = bf2f((ushort_t)(kv >> 16)) * ik * kg1;
        float ang = (float)srow * invf, sn, cs;
        sincosf(ang, &sn, &cs);
        *reinterpret_cast<unsigned int*>(&q_io[off]) = packbf(q0 * cs - q1 * sn, q0 * sn + q1 * cs);
        *reinterpret_cast<unsigned int*>(&k_io[off]) = packbf(k0v * cs - k1v * sn, k0v * sn + k1v * cs);
    }
}

// ---------- k2a: scores GEMM (BK=64) -> P + row sums l; XCD-affine grid ----------
__global__ __launch_bounds__(256) void k2a_rowsum(
    const ushort_t* __restrict__ qb, const ushort_t* __restrict__ kb,
    ushort_t* __restrict__ P, float* __restrict__ l)
{
    __shared__ ushort_t As[128 * LDP2];
    __shared__ ushort_t Bs[128 * LDP2];
    const int t = threadIdx.x;
    const int lane = t & 63, w = t >> 6;
    const int lm = lane & 15, lq = lane >> 4;
    const int wm = w >> 1, wn = w & 1;
    const int sr = t >> 3, sc = (t & 7) * 8;
    const int b  = blockIdx.x;
    const int qt = blockIdx.y;
    const int kt = blockIdx.z;

    const ushort_t* Ag = qb + ((size_t)b * SS + qt * 128) * DDIM;
    const ushort_t* Bg = kb + ((size_t)b * SS + kt * 128) * DDIM;

    f32x4 acc[4][4];
    #pragma unroll
    for (int i = 0; i < 4; i++)
        #pragma unroll
        for (int j = 0; j < 4; j++) acc[i][j] = (f32x4){0.f, 0.f, 0.f, 0.f};

    uint4 ra0, ra1, ra2, ra3, rb0, rb1, rb2, rb3;
    #define LOADAB3(dc) { \
        int ko_ = (dc) * 64 + sc; \
        ra0 = *reinterpret_cast<const uint4*>(&Ag[(size_t)sr * DDIM + ko_]); \
        ra1 = *reinterpret_cast<const uint4*>(&Ag[(size_t)(sr + 32) * DDIM + ko_]); \
        ra2 = *reinterpret_cast<const uint4*>(&Ag[(size_t)(sr + 64) * DDIM + ko_]); \
        ra3 = *reinterpret_cast<const uint4*>(&Ag[(size_t)(sr + 96) * DDIM + ko_]); \
        rb0 = *reinterpret_cast<const uint4*>(&Bg[(size_t)sr * DDIM + ko_]); \
        rb1 = *reinterpret_cast<const uint4*>(&Bg[(size_t)(sr + 32) * DDIM + ko_]); \
        rb2 = *reinterpret_cast<const uint4*>(&Bg[(size_t)(sr + 64) * DDIM + ko_]); \
        rb3 = *reinterpret_cast<const uint4*>(&Bg[(size_t)(sr + 96) * DDIM + ko_]); }

    LOADAB3(0);
    for (int dc = 0; dc < 8; dc++) {
        *reinterpret_cast<uint4*>(&As[(sr)      * LDP2 + sc]) = ra0;
        *reinterpret_cast<uint4*>(&As[(sr + 32) * LDP2 + sc]) = ra1;
        *reinterpret_cast<uint4*>(&As[(sr + 64) * LDP2 + sc]) = ra2;
        *reinterpret_cast<uint4*>(&As[(sr + 96) * LDP2 + sc]) = ra3;
        *reinterpret_cast<uint4*>(&Bs[(sr)      * LDP2 + sc]) = rb0;
        *reinterpret_cast<uint4*>(&Bs[(sr + 32) * LDP2 + sc]) = rb1;
        *reinterpret_cast<uint4*>(&Bs[(sr + 64) * LDP2 + sc]) = rb2;
        *reinterpret_cast<uint4*>(&Bs[(sr + 96) * LDP2 + sc]) = rb3;
        __syncthreads();
        if (dc < 7) LOADAB3(dc + 1);
        #pragma unroll
        for (int half = 0; half < 2; half++) {
            short8 af0 = ldfrag2(As, wm * 64 +  0 + lm, half * 32 + lq * 8);
            short8 af1 = ldfrag2(As, wm * 64 + 16 + lm, half * 32 + lq * 8);
            short8 af2 = ldfrag2(As, wm * 64 + 32 + lm, half * 32 + lq * 8);
            short8 af3 = ldfrag2(As, wm * 64 + 48 + lm, half * 32 + lq * 8);
            #pragma unroll
            for (int nt = 0; nt < 4; nt++) {
                short8 bfv = ldfrag2(Bs, wn * 64 + nt * 16 + lm, half * 32 + lq * 8);
                acc[0][nt] = __builtin_amdgcn_mfma_f32_16x16x32_bf16(af0, bfv, acc[0][nt], 0, 0, 0);
                acc[1][nt] = __builtin_amdgcn_mfma_f32_16x16x32_bf16(af1, bfv, acc[1][nt], 0, 0, 0);
                acc[2][nt] = __builtin_amdgcn_mfma_f32_16x16x32_bf16(af2, bfv, acc[2][nt], 0, 0, 0);
                acc[3][nt] = __builtin_amdgcn_mfma_f32_16x16x32_bf16(af3, bfv, acc[3][nt], 0, 0, 0);
            }
        }
        __syncthreads();
    }
    #undef LOADAB3

    const int rbase = qt * 128 + wm * 64;
    const int cbase = kt * 128 + wn * 64;
    ushort_t* Pb = P + (size_t)b * SS * SS;
    float* lrow = l + (size_t)b * SS;
    #pragma unroll
    for (int mt = 0; mt < 4; mt++) {
        #pragma unroll
        for (int r = 0; r < 4; r++) {
            const int row = rbase + mt * 16 + lq * 4 + r;
            float rowp = 0.f;
            #pragma unroll
            for (int nt = 0; nt < 4; nt++) {
                float e = __expf(acc[mt][nt][r] * SCALE);
                Pb[(size_t)row * SS + cbase + nt * 16 + lm] = f2bf(e);
                rowp += e;
            }
            float p = rowp;
            p += __shfl_xor(p, 1, 64); p += __shfl_xor(p, 2, 64);
            p += __shfl_xor(p, 4, 64); p += __shfl_xor(p, 8, 64);
            if (lm == 0) atomicAdd(&lrow[row], p);
        }
    }
}

// ---------- k2c: cw[k] = sum_q P[q][k] / l[q] ----------
__global__ __launch_bounds__(256) void k2c_colred(
    const ushort_t* __restrict__ P, const float* __restrict__ l,
    float* __restrict__ cw)
{
    const int t = threadIdx.x;
    const int b = blockIdx.z;
    const int k0 = blockIdx.x * 1024 + t * 4;
    const int q0 = blockIdx.y * 128;
    const ushort_t* Pb = P + ((size_t)b * SS + q0) * SS;
    const float* lb = l + (size_t)b * SS + q0;
    float a0 = 0.f, a1 = 0.f, a2 = 0.f, a3 = 0.f;
    for (int q = 0; q < 128; q++) {
        float rl = 1.0f / lb[q];
        uint2 pp = *reinterpret_cast<const uint2*>(&Pb[(size_t)q * SS + k0]);
        a0 = fmaf(bf2f((ushort_t)(pp.x & 0xFFFF)), rl, a0);
        a1 = fmaf(bf2f((ushort_t)(pp.x >> 16)), rl, a1);
        a2 = fmaf(bf2f((ushort_t)(pp.y & 0xFFFF)), rl, a2);
        a3 = fmaf(bf2f((ushort_t)(pp.y >> 16)), rl, a3);
    }
    atomicAdd(&cw[(size_t)b * SS + k0], a0);
    atomicAdd(&cw[(size_t)b * SS + k0 + 1], a1);
    atomicAdd(&cw[(size_t)b * SS + k0 + 2], a2);
    atomicAdd(&cw[(size_t)b * SS + k0 + 3], a3);
}

// ---------- k4: out = (xsum + sum_k cw*v) / S ----------
__global__ __launch_bounds__(256) void k4_out(
    const float* __restrict__ xsum, const ushort_t* __restrict__ v,
    const float* __restrict__ cwv, float* __restrict__ out)
{
    const int b = blockIdx.x, c = blockIdx.y;
    const int t = threadIdx.x;
    const int srow0 = c * (SS / 16);
    const ushort_t* vb = v + ((size_t)b * SS + srow0) * DDIM;
    const float* cwb   = cwv + (size_t)b * SS + srow0;
    float a0 = (c == 0) ? xsum[b * DDIM + t]       : 0.f;
    float a1 = (c == 0) ? xsum[b * DDIM + t + 256] : 0.f;
    for (int r = 0; r < SS / 16; r++) {
        float w = cwb[r];
        a0 += w * bf2f(vb[(size_t)r * DDIM + t]);
        a1 += w * bf2f(vb[(size_t)r * DDIM + t + 256]);
    }
    atomicAdd(&out[b * DDIM + t],       a0 * (1.0f / SS));
    atomicAdd(&out[b * DDIM + t + 256], a1 * (1.0f / SS));
}

extern "C" void kernel_launch(void* const* d_in, const int* in_sizes, int n_in,
                              void* d_out, int out_size, void* d_ws, size_t ws_size,
                              hipStream_t stream)
{
    const float* x      = (const float*)d_in[0];
    const float* conv_w = (const float*)d_in[1];
    const float* conv_b = (const float*)d_in[2];
    const float* pre_g  = (const float*)d_in[3];
    const float* q_g    = (const float*)d_in[4];
    const float* k_g    = (const float*)d_in[5];
    const float* Wq     = (const float*)d_in[6];
    const float* Wk     = (const float*)d_in[7];
    const float* Wv     = (const float*)d_in[8];
    float* out          = (float*)d_out;

    const size_t NTOK = (size_t)BB * SS * DDIM;   // 8.39M elements
    char* p = (char*)d_ws;
    ushort_t* xbf = (ushort_t*)p; p += NTOK * 2;
    ushort_t* ybf = (ushort_t*)p; p += NTOK * 2;
    ushort_t* xn  = (ushort_t*)p; p += NTOK * 2;
    /* pad */                     p += NTOK * 2;
    ushort_t* qio = (ushort_t*)p; p += NTOK * 2;
    ushort_t* kio = (ushort_t*)p; p += NTOK * 2;
    ushort_t* vb  = (ushort_t*)p; p += NTOK * 2;
    ushort_t* wcat = (ushort_t*)p; p += (size_t)DDIM * KC * 2;
    ushort_t* wqkv = (ushort_t*)p; p += (size_t)KC * DDIM * 2;
    float* rs   = (float*)p; p += (size_t)BB * SS * 4;
    float* rq   = (float*)p; p += (size_t)BB * SS * 4;
    float* rk   = (float*)p; p += (size_t)BB * SS * 4;
    float* lbuf = (float*)p; p += (size_t)BB * SS * 4;
    float* cwb  = (float*)p; p += (size_t)BB * SS * 4;
    float* xsum = (float*)p; p += (size_t)BB * DDIM * 4;

    ushort_t* Pbuf = xbf;   // 67.1 MB aliased region (xbf/ybf/xn/pad dead by k2a)

    (void)hipMemsetAsync(d_out, 0, (size_t)out_size * sizeof(float), stream);
    (void)hipMemsetAsync(rs, 0, ((size_t)BB * SS * 5 + (size_t)BB * DDIM) * sizeof(float), stream);

    kx_cast<<<dim3(SS / 16, BB), 256, 0, stream>>>(x, xbf, xsum);
    k0_prep<<<dim3(DDIM * KC / 256), 256, 0, stream>>>(conv_w, Wq, Wk, Wv, wcat, wqkv);
    k1b_conv<<<dim3(SS / 128, 4, BB), 256, 0, stream>>>(xbf, wcat, conv_b, ybf, rs);
    k1n_norm<<<dim3(SS / 8, BB), 256, 0, stream>>>(ybf, rs, pre_g, xn);
    k1c_qkv<<<dim3(SS / 128, 12, BB), 256, 0, stream>>>(xn, wqkv, qio, kio, vb, rq, rk);
    k1d_rope<<<dim3(SS / 8, BB), 256, 0, stream>>>(qio, kio, rq, rk, q_g, k_g);
    k2a_rowsum<<<dim3(BB, SS / 128, SS / 128), 256, 0, stream>>>(qio, kio, Pbuf, lbuf);
    k2c_colred<<<dim3(SS / 1024, SS / 128, BB), 256, 0, stream>>>(Pbuf, lbuf, cwb);
    k4_out<<<dim3(BB, 16), 256, 0, stream>>>(xsum, vb, cwb, out);
}

// Round 14
// 282.719 us; speedup vs baseline: 2.0757x; 1.0235x over previous
//
#include <hip/hip_runtime.h>
#include <math.h>

#define BB 8
#define SS 2048
#define DDIM 512
#define KC 1536
#define EPSV 1e-6f
#define SCALE 0.044194173824159216f   // 1/sqrt(512)
#define LDP  40   // BK=32 padded row (k2a) — measured best for the 16-iter score GEMM
#define LDP2 72   // BK=64 padded row (k1b/k1c) — fewer barrier drains wins at long K

typedef unsigned short ushort_t;
using short8 = __attribute__((ext_vector_type(8))) short;
using f32x4  = __attribute__((ext_vector_type(4))) float;

__device__ inline unsigned short f2bf(float f) {
    union { float f; unsigned int u; } v; v.f = f;
    unsigned int r = v.u + 0x7FFFu + ((v.u >> 16) & 1u);   // RNE
    return (unsigned short)(r >> 16);
}
__device__ inline unsigned int packbf(float a, float b) {
    return (unsigned int)f2bf(a) | ((unsigned int)f2bf(b) << 16);
}
__device__ inline float bf2f(unsigned short s) {
    union { unsigned int u; float f; } v; v.u = ((unsigned int)s) << 16; return v.f;
}
__device__ inline short8 ldfrag(const ushort_t* s, int row, int ko) {
    return *reinterpret_cast<const short8*>(&s[row * LDP + ko]);
}
__device__ inline short8 ldfrag2(const ushort_t* s, int row, int ko) {
    return *reinterpret_cast<const short8*>(&s[row * LDP2 + ko]);
}
__device__ inline uint4 lda_bc(const ushort_t* Ag, int s_, int ko) {
    return (s_ >= 0 && s_ < SS) ? *reinterpret_cast<const uint4*>(&Ag[(size_t)s_ * DDIM + ko])
                                : make_uint4(0, 0, 0, 0);
}

// ---------- kx: x fp32 -> bf16, plus xsum[b][d] = sum_s x ----------
__global__ __launch_bounds__(256) void kx_cast(const float* __restrict__ x,
                                               ushort_t* __restrict__ xbf,
                                               float* __restrict__ xsum)
{
    const int t = threadIdx.x;
    const int b = blockIdx.y;
    const int r0 = blockIdx.x * 16;
    const int c0 = 2 * t;
    float s0 = 0.f, s1 = 0.f;
    for (int r = 0; r < 16; r++) {
        size_t row = (size_t)b * SS + r0 + r;
        float2 v = *reinterpret_cast<const float2*>(&x[row * DDIM + c0]);
        s0 += v.x; s1 += v.y;
        *reinterpret_cast<unsigned int*>(&xbf[row * DDIM + c0]) = packbf(v.x, v.y);
    }
    atomicAdd(&xsum[b * DDIM + c0], s0);
    atomicAdd(&xsum[b * DDIM + c0 + 1], s1);
}

// ---------- k0: weights -> bf16 ----------
__global__ __launch_bounds__(256) void k0_prep(
    const float* __restrict__ conv_w, const float* __restrict__ Wq,
    const float* __restrict__ Wk, const float* __restrict__ Wv,
    ushort_t* __restrict__ wcat, ushort_t* __restrict__ wqkv)
{
    int idx = blockIdx.x * 256 + threadIdx.x;   // < 512*1536
    {
        int o = idx / KC, kk = idx - o * KC;
        int t = kk >> 9, i = kk & 511;
        wcat[idx] = f2bf(conv_w[(size_t)o * KC + i * 3 + t]);
    }
    {
        int n = idx >> 9, d = idx & 511;
        const float* src = (n < 512) ? &Wq[(size_t)n * DDIM + d]
                         : (n < 1024) ? &Wk[(size_t)(n - 512) * DDIM + d]
                         : &Wv[(size_t)(n - 1024) * DDIM + d];
        wqkv[idx] = f2bf(*src);
    }
}

// ---------- k1b: conv GEMM, BK=64 (K=1536) ----------
__global__ __launch_bounds__(256) void k1b_conv(
    const ushort_t* __restrict__ xbf, const ushort_t* __restrict__ wcat,
    const float* __restrict__ conv_b, ushort_t* __restrict__ ybf, float* __restrict__ rs)
{
    __shared__ ushort_t As[128 * LDP2];
    __shared__ ushort_t Bs[128 * LDP2];
    const int t = threadIdx.x;
    const int lane = t & 63, w = t >> 6;
    const int lm = lane & 15, lq = lane >> 4;
    const int wm = w >> 1, wn = w & 1;
    const int sr = t >> 3, sc = (t & 7) * 8;
    const int s0 = blockIdx.x * 128;
    const int n0 = blockIdx.y * 128;
    const int b  = blockIdx.z;
    const ushort_t* Ag = xbf + (size_t)b * SS * DDIM;
    const ushort_t* Bg = wcat + (size_t)n0 * KC;

    f32x4 acc[4][4];
    #pragma unroll
    for (int i = 0; i < 4; i++)
        #pragma unroll
        for (int j = 0; j < 4; j++) acc[i][j] = (f32x4){0.f, 0.f, 0.f, 0.f};

    uint4 ra0, ra1, ra2, ra3, rb0, rb1, rb2, rb3;
    #define LOADAB(dc) { \
        int tg_ = (dc) >> 3, ko_ = ((dc) & 7) * 64 + sc, kb_ = (dc) * 64 + sc; \
        int sa_ = s0 + sr + tg_ - 1; \
        ra0 = lda_bc(Ag, sa_,      ko_); ra1 = lda_bc(Ag, sa_ + 32, ko_); \
        ra2 = lda_bc(Ag, sa_ + 64, ko_); ra3 = lda_bc(Ag, sa_ + 96, ko_); \
        rb0 = *reinterpret_cast<const uint4*>(&Bg[(size_t)sr * KC + kb_]); \
        rb1 = *reinterpret_cast<const uint4*>(&Bg[(size_t)(sr + 32) * KC + kb_]); \
        rb2 = *reinterpret_cast<const uint4*>(&Bg[(size_t)(sr + 64) * KC + kb_]); \
        rb3 = *reinterpret_cast<const uint4*>(&Bg[(size_t)(sr + 96) * KC + kb_]); }

    LOADAB(0);
    for (int dc = 0; dc < 24; dc++) {
        *reinterpret_cast<uint4*>(&As[(sr)      * LDP2 + sc]) = ra0;
        *reinterpret_cast<uint4*>(&As[(sr + 32) * LDP2 + sc]) = ra1;
        *reinterpret_cast<uint4*>(&As[(sr + 64) * LDP2 + sc]) = ra2;
        *reinterpret_cast<uint4*>(&As[(sr + 96) * LDP2 + sc]) = ra3;
        *reinterpret_cast<uint4*>(&Bs[(sr)      * LDP2 + sc]) = rb0;
        *reinterpret_cast<uint4*>(&Bs[(sr + 32) * LDP2 + sc]) = rb1;
        *reinterpret_cast<uint4*>(&Bs[(sr + 64) * LDP2 + sc]) = rb2;
        *reinterpret_cast<uint4*>(&Bs[(sr + 96) * LDP2 + sc]) = rb3;
        __syncthreads();
        if (dc < 23) LOADAB(dc + 1);
        #pragma unroll
        for (int half = 0; half < 2; half++) {
            short8 af0 = ldfrag2(As, wm * 64 +  0 + lm, half * 32 + lq * 8);
            short8 af1 = ldfrag2(As, wm * 64 + 16 + lm, half * 32 + lq * 8);
            short8 af2 = ldfrag2(As, wm * 64 + 32 + lm, half * 32 + lq * 8);
            short8 af3 = ldfrag2(As, wm * 64 + 48 + lm, half * 32 + lq * 8);
            #pragma unroll
            for (int nt = 0; nt < 4; nt++) {
                short8 bfv = ldfrag2(Bs, wn * 64 + nt * 16 + lm, half * 32 + lq * 8);
                acc[0][nt] = __builtin_amdgcn_mfma_f32_16x16x32_bf16(af0, bfv, acc[0][nt], 0, 0, 0);
                acc[1][nt] = __builtin_amdgcn_mfma_f32_16x16x32_bf16(af1, bfv, acc[1][nt], 0, 0, 0);
                acc[2][nt] = __builtin_amdgcn_mfma_f32_16x16x32_bf16(af2, bfv, acc[2][nt], 0, 0, 0);
                acc[3][nt] = __builtin_amdgcn_mfma_f32_16x16x32_bf16(af3, bfv, acc[3][nt], 0, 0, 0);
            }
        }
        __syncthreads();
    }
    #undef LOADAB

    const int rbase = s0 + wm * 64;
    const int cbase = n0 + wn * 64;
    ushort_t* yb = ybf + (size_t)b * SS * DDIM;
    float* rsb = rs + (size_t)b * SS;
    float bias[4];
    #pragma unroll
    for (int nt = 0; nt < 4; nt++) bias[nt] = conv_b[cbase + nt * 16 + lm];
    #pragma unroll
    for (int mt = 0; mt < 4; mt++) {
        float pr[4] = {0.f, 0.f, 0.f, 0.f};
        #pragma unroll
        for (int nt = 0; nt < 4; nt++) {
            #pragma unroll
            for (int r = 0; r < 4; r++) {
                float val = acc[mt][nt][r] + bias[nt];
                yb[(size_t)(rbase + mt * 16 + lq * 4 + r) * DDIM + cbase + nt * 16 + lm] = f2bf(val);
                pr[r] = fmaf(val, val, pr[r]);
            }
        }
        #pragma unroll
        for (int r = 0; r < 4; r++) {
            float p = pr[r];
            p += __shfl_xor(p, 1, 64); p += __shfl_xor(p, 2, 64);
            p += __shfl_xor(p, 4, 64); p += __shfl_xor(p, 8, 64);
            if (lm == 0) atomicAdd(&rsb[rbase + mt * 16 + lq * 4 + r], p);
        }
    }
}

// ---------- k1n: x_norm ----------
__global__ __launch_bounds__(256) void k1n_norm(
    const ushort_t* __restrict__ ybf, const float* __restrict__ rs,
    const float* __restrict__ pre_g, ushort_t* __restrict__ xnbf)
{
    const int t = threadIdx.x;
    const int b = blockIdx.y;
    const int r0 = blockIdx.x * 8;
    float2 pg = *reinterpret_cast<const float2*>(&pre_g[2 * t]);
    for (int r = 0; r < 8; r++) {
        size_t row = (size_t)b * SS + r0 + r;
        float inv = rsqrtf(rs[row] * (1.0f / DDIM) + EPSV);
        unsigned int yv = *reinterpret_cast<const unsigned int*>(&ybf[row * DDIM + 2 * t]);
        float v0 = bf2f((ushort_t)(yv & 0xFFFF)), v1 = bf2f((ushort_t)(yv >> 16));
        *reinterpret_cast<unsigned int*>(&xnbf[row * DDIM + 2 * t]) =
            packbf(v0 * inv * pg.x, v1 * inv * pg.y);
    }
}

// ---------- k1c: QKV GEMM, BK=64 ----------
__global__ __launch_bounds__(256) void k1c_qkv(
    const ushort_t* __restrict__ xnbf, const ushort_t* __restrict__ wqkv,
    ushort_t* __restrict__ qraw, ushort_t* __restrict__ kraw, ushort_t* __restrict__ vb,
    float* __restrict__ rq, float* __restrict__ rk)
{
    __shared__ ushort_t As[128 * LDP2];
    __shared__ ushort_t Bs[128 * LDP2];
    const int t = threadIdx.x;
    const int lane = t & 63, w = t >> 6;
    const int lm = lane & 15, lq = lane >> 4;
    const int wm = w >> 1, wn = w & 1;
    const int sr = t >> 3, sc = (t & 7) * 8;
    const int s0 = blockIdx.x * 128;
    const int n0 = blockIdx.y * 128;
    const int b  = blockIdx.z;
    const ushort_t* Ag = xnbf + ((size_t)b * SS + s0) * DDIM;
    const ushort_t* Bg = wqkv + (size_t)n0 * DDIM;

    f32x4 acc[4][4];
    #pragma unroll
    for (int i = 0; i < 4; i++)
        #pragma unroll
        for (int j = 0; j < 4; j++) acc[i][j] = (f32x4){0.f, 0.f, 0.f, 0.f};

    uint4 ra0, ra1, ra2, ra3, rb0, rb1, rb2, rb3;
    #define LOADAB2(dc) { \
        int ko_ = (dc) * 64 + sc; \
        ra0 = *reinterpret_cast<const uint4*>(&Ag[(size_t)sr * DDIM + ko_]); \
        ra1 = *reinterpret_cast<const uint4*>(&Ag[(size_t)(sr + 32) * DDIM + ko_]); \
        ra2 = *reinterpret_cast<const uint4*>(&Ag[(size_t)(sr + 64) * DDIM + ko_]); \
        ra3 = *reinterpret_cast<const uint4*>(&Ag[(size_t)(sr + 96) * DDIM + ko_]); \
        rb0 = *reinterpret_cast<const uint4*>(&Bg[(size_t)sr * DDIM + ko_]); \
        rb1 = *reinterpret_cast<const uint4*>(&Bg[(size_t)(sr + 32) * DDIM + ko_]); \
        rb2 = *reinterpret_cast<const uint4*>(&Bg[(size_t)(sr + 64) * DDIM + ko_]); \
        rb3 = *reinterpret_cast<const uint4*>(&Bg[(size_t)(sr + 96) * DDIM + ko_]); }

    LOADAB2(0);
    for (int dc = 0; dc < 8; dc++) {
        *reinterpret_cast<uint4*>(&As[(sr)      * LDP2 + sc]) = ra0;
        *reinterpret_cast<uint4*>(&As[(sr + 32) * LDP2 + sc]) = ra1;
        *reinterpret_cast<uint4*>(&As[(sr + 64) * LDP2 + sc]) = ra2;
        *reinterpret_cast<uint4*>(&As[(sr + 96) * LDP2 + sc]) = ra3;
        *reinterpret_cast<uint4*>(&Bs[(sr)      * LDP2 + sc]) = rb0;
        *reinterpret_cast<uint4*>(&Bs[(sr + 32) * LDP2 + sc]) = rb1;
        *reinterpret_cast<uint4*>(&Bs[(sr + 64) * LDP2 + sc]) = rb2;
        *reinterpret_cast<uint4*>(&Bs[(sr + 96) * LDP2 + sc]) = rb3;
        __syncthreads();
        if (dc < 7) LOADAB2(dc + 1);
        #pragma unroll
        for (int half = 0; half < 2; half++) {
            short8 af0 = ldfrag2(As, wm * 64 +  0 + lm, half * 32 + lq * 8);
            short8 af1 = ldfrag2(As, wm * 64 + 16 + lm, half * 32 + lq * 8);
            short8 af2 = ldfrag2(As, wm * 64 + 32 + lm, half * 32 + lq * 8);
            short8 af3 = ldfrag2(As, wm * 64 + 48 + lm, half * 32 + lq * 8);
            #pragma unroll
            for (int nt = 0; nt < 4; nt++) {
                short8 bfv = ldfrag2(Bs, wn * 64 + nt * 16 + lm, half * 32 + lq * 8);
                acc[0][nt] = __builtin_amdgcn_mfma_f32_16x16x32_bf16(af0, bfv, acc[0][nt], 0, 0, 0);
                acc[1][nt] = __builtin_amdgcn_mfma_f32_16x16x32_bf16(af1, bfv, acc[1][nt], 0, 0, 0);
                acc[2][nt] = __builtin_amdgcn_mfma_f32_16x16x32_bf16(af2, bfv, acc[2][nt], 0, 0, 0);
                acc[3][nt] = __builtin_amdgcn_mfma_f32_16x16x32_bf16(af3, bfv, acc[3][nt], 0, 0, 0);
            }
        }
        __syncthreads();
    }
    #undef LOADAB2

    const int which = blockIdx.y >> 2;              // 0=q 1=k 2=v
    const int rbase = s0 + wm * 64;
    const int cbase = ((blockIdx.y & 3) * 128) + wn * 64;
    if (which == 2) {
        ushort_t* vbb = vb + (size_t)b * SS * DDIM;
        #pragma unroll
        for (int mt = 0; mt < 4; mt++)
            #pragma unroll
            for (int nt = 0; nt < 4; nt++)
                #pragma unroll
                for (int r = 0; r < 4; r++)
                    vbb[(size_t)(rbase + mt * 16 + lq * 4 + r) * DDIM + cbase + nt * 16 + lm] =
                        f2bf(acc[mt][nt][r]);
    } else {
        ushort_t* db = (which ? kraw : qraw) + (size_t)b * SS * DDIM;
        float* rb = (which ? rk : rq) + (size_t)b * SS;
        #pragma unroll
        for (int mt = 0; mt < 4; mt++) {
            float pr[4] = {0.f, 0.f, 0.f, 0.f};
            #pragma unroll
            for (int nt = 0; nt < 4; nt++) {
                #pragma unroll
                for (int r = 0; r < 4; r++) {
                    float val = acc[mt][nt][r];
                    db[(size_t)(rbase + mt * 16 + lq * 4 + r) * DDIM + cbase + nt * 16 + lm] = f2bf(val);
                    pr[r] = fmaf(val, val, pr[r]);
                }
            }
            #pragma unroll
            for (int r = 0; r < 4; r++) {
                float p = pr[r];
                p += __shfl_xor(p, 1, 64); p += __shfl_xor(p, 2, 64);
                p += __shfl_xor(p, 4, 64); p += __shfl_xor(p, 8, 64);
                if (lm == 0) atomicAdd(&rb[rbase + mt * 16 + lq * 4 + r], p);
            }
        }
    }
}

// ---------- k1d: rmsnorm(q,k) + rope, in-place ----------
__global__ __launch_bounds__(256) void k1d_rope(
    ushort_t* q_io, ushort_t* k_io,
    const float* __restrict__ rq, const float* __restrict__ rk,
    const float* __restrict__ q_g, const float* __restrict__ k_g)
{
    const int t = threadIdx.x;
    const int b = blockIdx.y;
    const int r0 = blockIdx.x * 8;
    const int c0 = 2 * t;
    float qg0 = q_g[c0], qg1 = q_g[c0 + 1];
    float kg0 = k_g[c0], kg1 = k_g[c0 + 1];
    float invf = (float)pow(10000.0, -(double)c0 / (double)DDIM);
    for (int r = 0; r < 8; r++) {
        int srow = r0 + r;
        size_t rowi = (size_t)b * SS + srow;
        float iq = rsqrtf(rq[rowi] * (1.0f / DDIM) + EPSV);
        float ik = rsqrtf(rk[rowi] * (1.0f / DDIM) + EPSV);
        size_t off = rowi * DDIM + c0;
        unsigned int qv = *reinterpret_cast<const unsigned int*>(&q_io[off]);
        unsigned int kv = *reinterpret_cast<const unsigned int*>(&k_io[off]);
        float q0 = bf2f((ushort_t)(qv & 0xFFFF)) * iq * qg0;
        float q1 = bf2f((ushort_t)(qv >> 16)) * iq * qg1;
        float k0v = bf2f((ushort_t)(kv & 0xFFFF)) * ik * kg0;
        float k1v = bf2f((ushort_t)(kv >> 16)) * ik * kg1;
        float ang = (float)srow * invf, sn, cs;
        sincosf(ang, &sn, &cs);
        *reinterpret_cast<unsigned int*>(&q_io[off]) = packbf(q0 * cs - q1 * sn, q0 * sn + q1 * cs);
        *reinterpret_cast<unsigned int*>(&k_io[off]) = packbf(k0v * cs - k1v * sn, k0v * sn + k1v * cs);
    }
}

// ---------- k2a: scores GEMM (BK=32, LDP=40 — R11 config) -> P + row sums l ----------
// Grid (BB, qtile, ktile): block id % 8 == batch -> XCD-affine; per-batch Q+K fits L2.
__global__ __launch_bounds__(256, 4) void k2a_rowsum(
    const ushort_t* __restrict__ qb, const ushort_t* __restrict__ kb,
    ushort_t* __restrict__ P, float* __restrict__ l)
{
    __shared__ ushort_t As[128 * LDP];
    __shared__ ushort_t Bs[128 * LDP];
    const int t = threadIdx.x;
    const int lane = t & 63, w = t >> 6;
    const int lm = lane & 15, lq = lane >> 4;
    const int wm = w >> 1, wn = w & 1;
    const int srow = t >> 2, scol = (t & 3) * 8;
    const int b  = blockIdx.x;
    const int qt = blockIdx.y;
    const int kt = blockIdx.z;

    const ushort_t* Ag = qb + ((size_t)b * SS + qt * 128) * DDIM;
    const ushort_t* Bg = kb + ((size_t)b * SS + kt * 128) * DDIM;

    f32x4 acc[4][4];
    #pragma unroll
    for (int i = 0; i < 4; i++)
        #pragma unroll
        for (int j = 0; j < 4; j++) acc[i][j] = (f32x4){0.f, 0.f, 0.f, 0.f};

    uint4 ra0 = *reinterpret_cast<const uint4*>(&Ag[(size_t)srow * DDIM + scol]);
    uint4 ra1 = *reinterpret_cast<const uint4*>(&Ag[(size_t)(srow + 64) * DDIM + scol]);
    uint4 rb0 = *reinterpret_cast<const uint4*>(&Bg[(size_t)srow * DDIM + scol]);
    uint4 rb1 = *reinterpret_cast<const uint4*>(&Bg[(size_t)(srow + 64) * DDIM + scol]);

    for (int dc = 0; dc < 16; dc++) {
        *reinterpret_cast<uint4*>(&As[srow * LDP + scol]) = ra0;
        *reinterpret_cast<uint4*>(&As[(srow + 64) * LDP + scol]) = ra1;
        *reinterpret_cast<uint4*>(&Bs[srow * LDP + scol]) = rb0;
        *reinterpret_cast<uint4*>(&Bs[(srow + 64) * LDP + scol]) = rb1;
        __syncthreads();
        if (dc < 15) {
            int off = (dc + 1) * 32 + scol;
            ra0 = *reinterpret_cast<const uint4*>(&Ag[(size_t)srow * DDIM + off]);
            ra1 = *reinterpret_cast<const uint4*>(&Ag[(size_t)(srow + 64) * DDIM + off]);
            rb0 = *reinterpret_cast<const uint4*>(&Bg[(size_t)srow * DDIM + off]);
            rb1 = *reinterpret_cast<const uint4*>(&Bg[(size_t)(srow + 64) * DDIM + off]);
        }
        short8 af[4];
        #pragma unroll
        for (int mt = 0; mt < 4; mt++)
            af[mt] = ldfrag(As, wm * 64 + mt * 16 + lm, lq * 8);
        #pragma unroll
        for (int nt = 0; nt < 4; nt++) {
            short8 bfv = ldfrag(Bs, wn * 64 + nt * 16 + lm, lq * 8);
            #pragma unroll
            for (int mt = 0; mt < 4; mt++)
                acc[mt][nt] = __builtin_amdgcn_mfma_f32_16x16x32_bf16(af[mt], bfv, acc[mt][nt], 0, 0, 0);
        }
        __syncthreads();
    }

    const int rbase = qt * 128 + wm * 64;
    const int cbase = kt * 128 + wn * 64;
    ushort_t* Pb = P + (size_t)b * SS * SS;
    float* lrow = l + (size_t)b * SS;
    #pragma unroll
    for (int mt = 0; mt < 4; mt++) {
        #pragma unroll
        for (int r = 0; r < 4; r++) {
            const int row = rbase + mt * 16 + lq * 4 + r;
            float rowp = 0.f;
            #pragma unroll
            for (int nt = 0; nt < 4; nt++) {
                float e = __expf(acc[mt][nt][r] * SCALE);
                Pb[(size_t)row * SS + cbase + nt * 16 + lm] = f2bf(e);
                rowp += e;
            }
            float p = rowp;
            p += __shfl_xor(p, 1, 64); p += __shfl_xor(p, 2, 64);
            p += __shfl_xor(p, 4, 64); p += __shfl_xor(p, 8, 64);
            if (lm == 0) atomicAdd(&lrow[row], p);
        }
    }
}

// ---------- k2c: cw[k] = sum_q P[q][k] / l[q] ----------
__global__ __launch_bounds__(256) void k2c_colred(
    const ushort_t* __restrict__ P, const float* __restrict__ l,
    float* __restrict__ cw)
{
    const int t = threadIdx.x;
    const int b = blockIdx.z;
    const int k0 = blockIdx.x * 1024 + t * 4;
    const int q0 = blockIdx.y * 128;
    const ushort_t* Pb = P + ((size_t)b * SS + q0) * SS;
    const float* lb = l + (size_t)b * SS + q0;
    float a0 = 0.f, a1 = 0.f, a2 = 0.f, a3 = 0.f;
    for (int q = 0; q < 128; q++) {
        float rl = 1.0f / lb[q];
        uint2 pp = *reinterpret_cast<const uint2*>(&Pb[(size_t)q * SS + k0]);
        a0 = fmaf(bf2f((ushort_t)(pp.x & 0xFFFF)), rl, a0);
        a1 = fmaf(bf2f((ushort_t)(pp.x >> 16)), rl, a1);
        a2 = fmaf(bf2f((ushort_t)(pp.y & 0xFFFF)), rl, a2);
        a3 = fmaf(bf2f((ushort_t)(pp.y >> 16)), rl, a3);
    }
    atomicAdd(&cw[(size_t)b * SS + k0], a0);
    atomicAdd(&cw[(size_t)b * SS + k0 + 1], a1);
    atomicAdd(&cw[(size_t)b * SS + k0 + 2], a2);
    atomicAdd(&cw[(size_t)b * SS + k0 + 3], a3);
}

// ---------- k4: out = (xsum + sum_k cw*v) / S ----------
__global__ __launch_bounds__(256) void k4_out(
    const float* __restrict__ xsum, const ushort_t* __restrict__ v,
    const float* __restrict__ cwv, float* __restrict__ out)
{
    const int b = blockIdx.x, c = blockIdx.y;
    const int t = threadIdx.x;
    const int srow0 = c * (SS / 16);
    const ushort_t* vb = v + ((size_t)b * SS + srow0) * DDIM;
    const float* cwb   = cwv + (size_t)b * SS + srow0;
    float a0 = (c == 0) ? xsum[b * DDIM + t]       : 0.f;
    float a1 = (c == 0) ? xsum[b * DDIM + t + 256] : 0.f;
    for (int r = 0; r < SS / 16; r++) {
        float w = cwb[r];
        a0 += w * bf2f(vb[(size_t)r * DDIM + t]);
        a1 += w * bf2f(vb[(size_t)r * DDIM + t + 256]);
    }
    atomicAdd(&out[b * DDIM + t],       a0 * (1.0f / SS));
    atomicAdd(&out[b * DDIM + t + 256], a1 * (1.0f / SS));
}

extern "C" void kernel_launch(void* const* d_in, const int* in_sizes, int n_in,
                              void* d_out, int out_size, void* d_ws, size_t ws_size,
                              hipStream_t stream)
{
    const float* x      = (const float*)d_in[0];
    const float* conv_w = (const float*)d_in[1];
    const float* conv_b = (const float*)d_in[2];
    const float* pre_g  = (const float*)d_in[3];
    const float* q_g    = (const float*)d_in[4];
    const float* k_g    = (const float*)d_in[5];
    const float* Wq     = (const float*)d_in[6];
    const float* Wk     = (const float*)d_in[7];
    const float* Wv     = (const float*)d_in[8];
    float* out          = (float*)d_out;

    const size_t NTOK = (size_t)BB * SS * DDIM;   // 8.39M elements
    char* p = (char*)d_ws;
    ushort_t* xbf = (ushort_t*)p; p += NTOK * 2;
    ushort_t* ybf = (ushort_t*)p; p += NTOK * 2;
    ushort_t* xn  = (ushort_t*)p; p += NTOK * 2;
    /* pad */                     p += NTOK * 2;
    ushort_t* qio = (ushort_t*)p; p += NTOK * 2;
    ushort_t* kio = (ushort_t*)p; p += NTOK * 2;
    ushort_t* vb  = (ushort_t*)p; p += NTOK * 2;
    ushort_t* wcat = (ushort_t*)p; p += (size_t)DDIM * KC * 2;
    ushort_t* wqkv = (ushort_t*)p; p += (size_t)KC * DDIM * 2;
    float* rs   = (float*)p; p += (size_t)BB * SS * 4;
    float* rq   = (float*)p; p += (size_t)BB * SS * 4;
    float* rk   = (float*)p; p += (size_t)BB * SS * 4;
    float* lbuf = (float*)p; p += (size_t)BB * SS * 4;
    float* cwb  = (float*)p; p += (size_t)BB * SS * 4;
    float* xsum = (float*)p; p += (size_t)BB * DDIM * 4;

    ushort_t* Pbuf = xbf;   // 67.1 MB aliased region (xbf/ybf/xn/pad dead by k2a)

    (void)hipMemsetAsync(d_out, 0, (size_t)out_size * sizeof(float), stream);
    (void)hipMemsetAsync(rs, 0, ((size_t)BB * SS * 5 + (size_t)BB * DDIM) * sizeof(float), stream);

    kx_cast<<<dim3(SS / 16, BB), 256, 0, stream>>>(x, xbf, xsum);
    k0_prep<<<dim3(DDIM * KC / 256), 256, 0, stream>>>(conv_w, Wq, Wk, Wv, wcat, wqkv);
    k1b_conv<<<dim3(SS / 128, 4, BB), 256, 0, stream>>>(xbf, wcat, conv_b, ybf, rs);
    k1n_norm<<<dim3(SS / 8, BB), 256, 0, stream>>>(ybf, rs, pre_g, xn);
    k1c_qkv<<<dim3(SS / 128, 12, BB), 256, 0, stream>>>(xn, wqkv, qio, kio, vb, rq, rk);
    k1d_rope<<<dim3(SS / 8, BB), 256, 0, stream>>>(qio, kio, rq, rk, q_g, k_g);
    k2a_rowsum<<<dim3(BB, SS / 128, SS / 128), 256, 0, stream>>>(qio, kio, Pbuf, lbuf);
    k2c_colred<<<dim3(SS / 1024, SS / 128, BB), 256, 0, stream>>>(Pbuf, lbuf, cwb);
    k4_out<<<dim3(BB, 16), 256, 0, stream>>>(xsum, vb, cwb, out);
}